// Round 3
// baseline (1210.649 us; speedup 1.0000x reference)
//
#include <hip/hip_runtime.h>
#include <math.h>

// Problem constants (from reference)
#define HH 256
#define WW 256
#define CC 32
#define SS 32
#define NRAYS 32768            // N*R = 2*16384
#define RAYS_PER_BLOCK 8
#define NWTS 4257              // 2048 + 64 + 2112 + 33

// ---------- helpers ----------
__device__ __forceinline__ float bf2f(unsigned short u) {
    union { unsigned int ui; float f; } v; v.ui = ((unsigned int)u) << 16; return v.f;
}
__device__ __forceinline__ unsigned short f2bf(float f) {
    union { float f; unsigned int u; } v; v.f = f;
    unsigned int u = v.u;
    unsigned int r = u + 0x7fffu + ((u >> 16) & 1u);   // round-to-nearest-even
    return (unsigned short)(r >> 16);
}
__device__ __forceinline__ int iclamp(int x, int lo, int hi) {
    return x < lo ? lo : (x > hi ? hi : x);
}
__device__ __forceinline__ float softplus_f(float z) {
    return fmaxf(z, 0.f) + log1pf(expf(-fabsf(z)));
}

template<bool F32>
__device__ __forceinline__ float ldv(const void* p, size_t i) {
    if (F32) return ((const float*)p)[i];
    else     return bf2f(((const unsigned short*)p)[i]);
}

// ---------- dtype detection: |ray_origin| == 2.7 exactly (by construction) ----------
__global__ void detect_dtype(const void* __restrict__ rayo, int* __restrict__ flag) {
    if (threadIdx.x == 0 && blockIdx.x == 0) {
        const float* f = (const float*)rayo;
        const unsigned short* u = (const unsigned short*)rayo;
        float sf = 0.f, sb = 0.f;
        for (int r = 0; r < 8; r++) {
            const float a = f[3 * r], b = f[3 * r + 1], c = f[3 * r + 2];
            const float nf = a * a + b * b + c * c;
            sf += fminf(fabsf(nf - 7.29f), 1e3f);       // fminf(NaN,x)=x -> NaN-safe clamp
            const float x = bf2f(u[3 * r]), y = bf2f(u[3 * r + 1]), z = bf2f(u[3 * r + 2]);
            const float nb = x * x + y * y + z * z;
            sb += fminf(fabsf(nb - 7.29f), 1e3f);
        }
        *flag = (sf < sb) ? 1 : 0;                      // 1 = inputs are float32
    }
}

// ---------- fused sample + MLP + ray march body, templated on input dtype ----------
template<bool F32>
__device__ __forceinline__ void render_body(
    const void* __restrict__ vol, const void* __restrict__ rayo,
    const void* __restrict__ rayd, const void* __restrict__ w1b,
    const void* __restrict__ b1b, const void* __restrict__ w2b,
    const void* __restrict__ b2b, void* __restrict__ outp,
    float* wsm, float (*rgbL)[SS][33], float (*sigL)[SS])
{
    const int t = threadIdx.x;

    // ---- stage weights -> f32 LDS ----
    for (int i = t; i < NWTS; i += 256) {
        float v;
        if (i < 2048)       v = ldv<F32>(w1b, i);
        else if (i < 2112)  v = ldv<F32>(b1b, i - 2048);
        else if (i < 4224)  v = ldv<F32>(w2b, i - 2112);
        else                v = ldv<F32>(b2b, i - 4224);
        wsm[i] = v;
    }
    __syncthreads();

    const int rl = t >> 5;         // ray in block (0..7)
    const int s  = t & 31;         // sample along ray
    const int gray = blockIdx.x * RAYS_PER_BLOCK + rl;   // 0..32767
    const int n = gray >> 14;      // batch index (0..1)

    // ---- ray + depth ----
    const size_t rbase = (size_t)gray * 3;
    const float ox = ldv<F32>(rayo, rbase),     oy = ldv<F32>(rayo, rbase + 1), oz = ldv<F32>(rayo, rbase + 2);
    const float dx = ldv<F32>(rayd, rbase),     dy = ldv<F32>(rayd, rbase + 1), dz = ldv<F32>(rayd, rbase + 2);
    const float d = 2.25f + 1.05f * ((s + 0.5f) * (1.0f / 32.0f));
    const float x = (ox + d * dx) * 2.0f;
    const float y = (oy + d * dy) * 2.0f;
    const float z = (oz + d * dz) * 2.0f;

    // ---- tri-plane bilinear gather from CHW, mean over planes ----
    float fx[32];
    #pragma unroll
    for (int c = 0; c < 32; c++) fx[c] = 0.f;

    #pragma unroll
    for (int p = 0; p < 3; p++) {
        // p0:(x,y)  p1:(y,z)  p2:(x,z)
        const float u = (p == 0) ? x : ((p == 1) ? y : x);
        const float v = (p == 0) ? y : z;
        const float ixf = (u + 1.0f) * 0.5f * 255.0f;
        const float iyf = (v + 1.0f) * 0.5f * 255.0f;
        const float ix0f = floorf(ixf), iy0f = floorf(iyf);
        const float wx1 = ixf - ix0f, wy1 = iyf - iy0f;
        const float wx0 = 1.f - wx1,  wy0 = 1.f - wy1;
        const int ix0 = iclamp((int)ix0f, 0, 255);
        const int ix1 = iclamp((int)ix0f + 1, 0, 255);
        const int iy0 = iclamp((int)iy0f, 0, 255);
        const int iy1 = iclamp((int)iy0f + 1, 0, 255);
        const float wnw = wx0 * wy0, wne = wx1 * wy0, wsw = wx0 * wy1, wse = wx1 * wy1;

        const int i00 = iy0 * WW + ix0, i01 = iy0 * WW + ix1;
        const int i10 = iy1 * WW + ix0, i11 = iy1 * WW + ix1;
        const size_t pb = (size_t)(n * 3 + p) * CC * HH * WW;
        #pragma unroll
        for (int c = 0; c < 32; c++) {
            const size_t cb = pb + (size_t)c * (HH * WW);
            fx[c] += wnw * ldv<F32>(vol, cb + i00) + wne * ldv<F32>(vol, cb + i01)
                   + wsw * ldv<F32>(vol, cb + i10) + wse * ldv<F32>(vol, cb + i11);
        }
    }
    #pragma unroll
    for (int c = 0; c < 32; c++) fx[c] *= (1.0f / 3.0f);

    // ---- MLP: 32 -> 64 (softplus) -> 33 ----
    const float* W1 = wsm;            // [32][64]
    const float* B1 = wsm + 2048;
    const float* W2 = wsm + 2112;     // [64][33]
    const float* B2 = wsm + 4224;

    float h[64];
    #pragma unroll
    for (int j = 0; j < 64; j++) h[j] = B1[j];
    #pragma unroll
    for (int c = 0; c < 32; c++) {
        const float f = fx[c];
        #pragma unroll
        for (int j = 0; j < 64; j++) h[j] = fmaf(f, W1[c * 64 + j], h[j]);
    }
    #pragma unroll
    for (int j = 0; j < 64; j++) h[j] = softplus_f(h[j]);

    #pragma unroll 1
    for (int k = 0; k < 33; k++) {
        float zz = B2[k];
        #pragma unroll
        for (int j = 0; j < 64; j++) zz = fmaf(h[j], W2[j * 33 + k], zz);
        if (k == 0) {
            sigL[rl][s] = zz;                       // raw sigma
        } else {
            const float sg = 1.0f / (1.0f + expf(-zz));
            rgbL[rl][s][k - 1] = fmaf(sg, 1.002f, -0.001f);
        }
    }
    __syncthreads();

    // ---- ray march: thread (rl, c) walks samples of ray rl ----
    const int c = t & 31;
    const float delta = 1.05f / 32.0f;
    float T = 1.0f, acc = 0.0f;
    float sig_prev = sigL[rl][0];
    float rgb_prev = rgbL[rl][0][c];
    #pragma unroll 1
    for (int sm = 0; sm < 31; sm++) {
        const float sig_next = sigL[rl][sm + 1];
        const float rgb_next = rgbL[rl][sm + 1][c];
        const float dm = 0.5f * (sig_prev + sig_next) - 1.0f;
        const float dens = softplus_f(dm);
        const float alpha = 1.0f - expf(-delta * dens);
        const float w = alpha * T;
        T *= (1.0f - alpha + 1e-10f);
        acc += w * 0.5f * (rgb_prev + rgb_next);
        sig_prev = sig_next;
        rgb_prev = rgb_next;
    }
    const size_t oidx = (size_t)gray * 32 + c;
    if (F32) ((float*)outp)[oidx] = acc;
    else     ((unsigned short*)outp)[oidx] = f2bf(acc);
}

__global__ __launch_bounds__(256) void render_any(
    const void* __restrict__ vol, const void* __restrict__ rayo,
    const void* __restrict__ rayd, const void* __restrict__ w1b,
    const void* __restrict__ b1b, const void* __restrict__ w2b,
    const void* __restrict__ b2b, void* __restrict__ outp,
    const int* __restrict__ flag)
{
    __shared__ float wsm[NWTS];
    __shared__ float rgbL[RAYS_PER_BLOCK][SS][33];
    __shared__ float sigL[RAYS_PER_BLOCK][SS];
    if (*flag) render_body<true >(vol, rayo, rayd, w1b, b1b, w2b, b2b, outp, wsm, rgbL, sigL);
    else       render_body<false>(vol, rayo, rayd, w1b, b1b, w2b, b2b, outp, wsm, rgbL, sigL);
}

extern "C" void kernel_launch(void* const* d_in, const int* in_sizes, int n_in,
                              void* d_out, int out_size, void* d_ws, size_t ws_size,
                              hipStream_t stream) {
    const void* vol  = d_in[0];
    const void* rayo = d_in[1];
    const void* rayd = d_in[2];
    const void* w1   = d_in[3];
    const void* b1   = d_in[4];
    const void* w2   = d_in[5];
    const void* b2   = d_in[6];
    int* flag = (int*)d_ws;

    detect_dtype<<<dim3(1), dim3(64), 0, stream>>>(rayo, flag);
    render_any<<<dim3(NRAYS / RAYS_PER_BLOCK), dim3(256), 0, stream>>>(
        vol, rayo, rayd, w1, b1, w2, b2, d_out, flag);
}

// Round 4
// 602.624 us; speedup vs baseline: 2.0090x; 2.0090x over previous
//
#include <hip/hip_runtime.h>
#include <math.h>

// Problem constants (from reference)
#define HH 256
#define WW 256
#define CC 32
#define SS 32
#define NRAYS 32768            // N*R = 2*16384
#define RAYS_PER_BLOCK 8
#define NWTS 4257              // 2048 + 64 + 2112 + 33
#define TEXOFF 256             // byte offset of HWC texture in d_ws (flag lives at 0)

// ---------- helpers ----------
__device__ __forceinline__ float bf2f(unsigned short u) {
    union { unsigned int ui; float f; } v; v.ui = ((unsigned int)u) << 16; return v.f;
}
__device__ __forceinline__ unsigned short f2bf(float f) {
    union { float f; unsigned int u; } v; v.f = f;
    unsigned int u = v.u;
    unsigned int r = u + 0x7fffu + ((u >> 16) & 1u);   // round-to-nearest-even
    return (unsigned short)(r >> 16);
}
__device__ __forceinline__ int iclamp(int x, int lo, int hi) {
    return x < lo ? lo : (x > hi ? hi : x);
}
__device__ __forceinline__ float softplus_f(float z) {
    return fmaxf(z, 0.f) + log1pf(expf(-fabsf(z)));
}

template<bool F32>
__device__ __forceinline__ float ldv(const void* p, size_t i) {
    if (F32) return ((const float*)p)[i];
    else     return bf2f(((const unsigned short*)p)[i]);
}

// ---------- dtype detection: |ray_origin| == 2.7 exactly (by construction) ----------
__global__ void detect_dtype(const void* __restrict__ rayo, int* __restrict__ flag) {
    if (threadIdx.x == 0 && blockIdx.x == 0) {
        const float* f = (const float*)rayo;
        const unsigned short* u = (const unsigned short*)rayo;
        float sf = 0.f, sb = 0.f;
        for (int r = 0; r < 8; r++) {
            const float a = f[3 * r], b = f[3 * r + 1], c = f[3 * r + 2];
            const float nf = a * a + b * b + c * c;
            sf += fminf(fabsf(nf - 7.29f), 1e3f);       // fminf(NaN,x)=x -> NaN-safe clamp
            const float x = bf2f(u[3 * r]), y = bf2f(u[3 * r + 1]), z = bf2f(u[3 * r + 2]);
            const float nb = x * x + y * y + z * z;
            sb += fminf(fabsf(nb - 7.29f), 1e3f);
        }
        *flag = (sf < sb) ? 1 : 0;                      // 1 = inputs are float32
    }
}

// ---------- CHW -> HWC transpose of the 6 planes (dtype via flag) ----------
__global__ __launch_bounds__(1024) void transpose_tex(
    const void* __restrict__ vol, void* __restrict__ tex, const int* __restrict__ flag) {
    __shared__ float          tf[32][33];
    __shared__ unsigned short tu[32][33];
    const int tx = threadIdx.x, ty = threadIdx.y;
    const int w0 = blockIdx.x * 32;
    const int h  = blockIdx.y;
    const int img = blockIdx.z;
    const size_t src = (((size_t)img * CC + ty) * HH + h) * WW + (w0 + tx);  // c=ty, w=w0+tx
    const size_t dst = (((size_t)img * HH + h) * WW + (w0 + ty)) * CC + tx;  // w=w0+ty, c=tx
    if (*flag) {
        tf[ty][tx] = ((const float*)vol)[src];
        __syncthreads();
        ((float*)tex)[dst] = tf[tx][ty];
    } else {
        tu[ty][tx] = ((const unsigned short*)vol)[src];
        __syncthreads();
        ((unsigned short*)tex)[dst] = tu[tx][ty];
    }
}

// ================= FAST PATH: lane-cooperative HWC gather =================
template<bool F32>
__device__ __forceinline__ void render_fast_body(
    const void* __restrict__ tex,   // [6][256][256][32] HWC
    const void* __restrict__ rayo, const void* __restrict__ rayd,
    const void* __restrict__ w1b, const void* __restrict__ b1b,
    const void* __restrict__ w2b, const void* __restrict__ b2b,
    void* __restrict__ outp,
    float* __restrict__ wsm,        // [NWTS]
    float* __restrict__ fxb,        // [256*33]  (fx rows; reused as rgb rows)
    float* __restrict__ sigL)       // [256]
{
    const int t = threadIdx.x;

    // ---- stage weights -> f32 LDS ----
    for (int i = t; i < NWTS; i += 256) {
        float v;
        if (i < 2048)       v = ldv<F32>(w1b, i);
        else if (i < 2112)  v = ldv<F32>(b1b, i - 2048);
        else if (i < 4224)  v = ldv<F32>(w2b, i - 2112);
        else                v = ldv<F32>(b2b, i - 4224);
        wsm[i] = v;
    }

    // ---- gather stage: group g (32 lanes) handles ray g; lane c = channel ----
    {
        const int c = t & 31;
        const int g = t >> 5;
        const int gray = blockIdx.x * RAYS_PER_BLOCK + g;
        const int n = gray >> 14;
        const size_t rbase = (size_t)gray * 3;
        const float ox = ldv<F32>(rayo, rbase), oy = ldv<F32>(rayo, rbase + 1), oz = ldv<F32>(rayo, rbase + 2);
        const float dx = ldv<F32>(rayd, rbase), dy = ldv<F32>(rayd, rbase + 1), dz = ldv<F32>(rayd, rbase + 2);

        #pragma unroll 1
        for (int s = 0; s < 32; ++s) {
            const float d = 2.25f + 1.05f * ((s + 0.5f) * (1.0f / 32.0f));
            const float x = (ox + d * dx) * 2.0f;
            const float y = (oy + d * dy) * 2.0f;
            const float z = (oz + d * dz) * 2.0f;
            float acc = 0.f;
            #pragma unroll
            for (int p = 0; p < 3; p++) {
                // p0:(x,y)  p1:(y,z)  p2:(x,z)
                const float u = (p == 0) ? x : ((p == 1) ? y : x);
                const float v = (p == 0) ? y : z;
                const float ixf = (u + 1.0f) * 0.5f * 255.0f;
                const float iyf = (v + 1.0f) * 0.5f * 255.0f;
                const float ix0f = floorf(ixf), iy0f = floorf(iyf);
                const float wx1 = ixf - ix0f, wy1 = iyf - iy0f;
                const float wx0 = 1.f - wx1,  wy0 = 1.f - wy1;
                const int ix0 = iclamp((int)ix0f, 0, 255);
                const int ix1 = iclamp((int)ix0f + 1, 0, 255);
                const int iy0 = iclamp((int)iy0f, 0, 255);
                const int iy1 = iclamp((int)iy0f + 1, 0, 255);
                const float wnw = wx0 * wy0, wne = wx1 * wy0, wsw = wx0 * wy1, wse = wx1 * wy1;
                const size_t pb = (size_t)(n * 3 + p) * HH * WW * CC;
                // one coalesced load per corner (lane c = channel)
                acc += wnw * ldv<F32>(tex, pb + ((size_t)iy0 * WW + ix0) * CC + c)
                     + wne * ldv<F32>(tex, pb + ((size_t)iy0 * WW + ix1) * CC + c)
                     + wsw * ldv<F32>(tex, pb + ((size_t)iy1 * WW + ix0) * CC + c)
                     + wse * ldv<F32>(tex, pb + ((size_t)iy1 * WW + ix1) * CC + c);
            }
            fxb[(g * 32 + s) * 33 + c] = acc * (1.0f / 3.0f);
        }
    }
    __syncthreads();

    // ---- MLP: thread t owns sample row t (ray t>>5, sample t&31) ----
    const int rl = t >> 5;
    const int s  = t & 31;
    const int gray = blockIdx.x * RAYS_PER_BLOCK + rl;

    float fx[32];
    #pragma unroll
    for (int c = 0; c < 32; c++) fx[c] = fxb[t * 33 + c];
    // (row t is only ever read/written by thread t until the next barrier)

    const float* W1 = wsm;            // [32][64]
    const float* B1 = wsm + 2048;
    const float* W2 = wsm + 2112;     // [64][33]
    const float* B2 = wsm + 4224;

    float h[64];
    #pragma unroll
    for (int j = 0; j < 64; j++) h[j] = B1[j];
    #pragma unroll
    for (int c = 0; c < 32; c++) {
        const float f = fx[c];
        #pragma unroll
        for (int j = 0; j < 64; j++) h[j] = fmaf(f, W1[c * 64 + j], h[j]);
    }
    #pragma unroll
    for (int j = 0; j < 64; j++) h[j] = softplus_f(h[j]);

    #pragma unroll 1
    for (int k = 0; k < 33; k++) {
        float zz = B2[k];
        #pragma unroll
        for (int j = 0; j < 64; j++) zz = fmaf(h[j], W2[j * 33 + k], zz);
        if (k == 0) {
            sigL[t] = zz;                         // raw sigma
        } else {
            const float sg = 1.0f / (1.0f + expf(-zz));
            fxb[t * 33 + (k - 1)] = fmaf(sg, 1.002f, -0.001f);   // rgb row t
        }
    }
    __syncthreads();

    // ---- ray march: thread (rl, c) walks samples of ray rl ----
    const int c = t & 31;
    const float delta = 1.05f / 32.0f;
    float T = 1.0f, acc = 0.0f;
    float sig_prev = sigL[rl * 32 + 0];
    float rgb_prev = fxb[(rl * 32 + 0) * 33 + c];
    #pragma unroll 1
    for (int sm = 0; sm < 31; sm++) {
        const float sig_next = sigL[rl * 32 + sm + 1];
        const float rgb_next = fxb[(rl * 32 + sm + 1) * 33 + c];
        const float dm = 0.5f * (sig_prev + sig_next) - 1.0f;
        const float dens = softplus_f(dm);
        const float alpha = 1.0f - expf(-delta * dens);
        const float w = alpha * T;
        T *= (1.0f - alpha + 1e-10f);
        acc += w * 0.5f * (rgb_prev + rgb_next);
        sig_prev = sig_next;
        rgb_prev = rgb_next;
    }
    const size_t oidx = (size_t)gray * 32 + c;
    if (F32) ((float*)outp)[oidx] = acc;
    else     ((unsigned short*)outp)[oidx] = f2bf(acc);
}

__global__ __launch_bounds__(256) void render_fast(
    const void* __restrict__ tex, const void* __restrict__ rayo,
    const void* __restrict__ rayd, const void* __restrict__ w1b,
    const void* __restrict__ b1b, const void* __restrict__ w2b,
    const void* __restrict__ b2b, void* __restrict__ outp,
    const int* __restrict__ flag)
{
    __shared__ float wsm[NWTS];
    __shared__ float fxb[256 * 33];
    __shared__ float sigL[256];
    if (*flag) render_fast_body<true >(tex, rayo, rayd, w1b, b1b, w2b, b2b, outp, wsm, fxb, sigL);
    else       render_fast_body<false>(tex, rayo, rayd, w1b, b1b, w2b, b2b, outp, wsm, fxb, sigL);
}

// ================= FALLBACK: round-3 direct-CHW kernel (verbatim) =================
template<bool F32>
__device__ __forceinline__ void render_body(
    const void* __restrict__ vol, const void* __restrict__ rayo,
    const void* __restrict__ rayd, const void* __restrict__ w1b,
    const void* __restrict__ b1b, const void* __restrict__ w2b,
    const void* __restrict__ b2b, void* __restrict__ outp,
    float* wsm, float (*rgbL)[SS][33], float (*sigL)[SS])
{
    const int t = threadIdx.x;

    for (int i = t; i < NWTS; i += 256) {
        float v;
        if (i < 2048)       v = ldv<F32>(w1b, i);
        else if (i < 2112)  v = ldv<F32>(b1b, i - 2048);
        else if (i < 4224)  v = ldv<F32>(w2b, i - 2112);
        else                v = ldv<F32>(b2b, i - 4224);
        wsm[i] = v;
    }
    __syncthreads();

    const int rl = t >> 5;
    const int s  = t & 31;
    const int gray = blockIdx.x * RAYS_PER_BLOCK + rl;
    const int n = gray >> 14;

    const size_t rbase = (size_t)gray * 3;
    const float ox = ldv<F32>(rayo, rbase),     oy = ldv<F32>(rayo, rbase + 1), oz = ldv<F32>(rayo, rbase + 2);
    const float dx = ldv<F32>(rayd, rbase),     dy = ldv<F32>(rayd, rbase + 1), dz = ldv<F32>(rayd, rbase + 2);
    const float d = 2.25f + 1.05f * ((s + 0.5f) * (1.0f / 32.0f));
    const float x = (ox + d * dx) * 2.0f;
    const float y = (oy + d * dy) * 2.0f;
    const float z = (oz + d * dz) * 2.0f;

    float fx[32];
    #pragma unroll
    for (int c = 0; c < 32; c++) fx[c] = 0.f;

    #pragma unroll
    for (int p = 0; p < 3; p++) {
        const float u = (p == 0) ? x : ((p == 1) ? y : x);
        const float v = (p == 0) ? y : z;
        const float ixf = (u + 1.0f) * 0.5f * 255.0f;
        const float iyf = (v + 1.0f) * 0.5f * 255.0f;
        const float ix0f = floorf(ixf), iy0f = floorf(iyf);
        const float wx1 = ixf - ix0f, wy1 = iyf - iy0f;
        const float wx0 = 1.f - wx1,  wy0 = 1.f - wy1;
        const int ix0 = iclamp((int)ix0f, 0, 255);
        const int ix1 = iclamp((int)ix0f + 1, 0, 255);
        const int iy0 = iclamp((int)iy0f, 0, 255);
        const int iy1 = iclamp((int)iy0f + 1, 0, 255);
        const float wnw = wx0 * wy0, wne = wx1 * wy0, wsw = wx0 * wy1, wse = wx1 * wy1;

        const int i00 = iy0 * WW + ix0, i01 = iy0 * WW + ix1;
        const int i10 = iy1 * WW + ix0, i11 = iy1 * WW + ix1;
        const size_t pb = (size_t)(n * 3 + p) * CC * HH * WW;
        #pragma unroll
        for (int c = 0; c < 32; c++) {
            const size_t cb = pb + (size_t)c * (HH * WW);
            fx[c] += wnw * ldv<F32>(vol, cb + i00) + wne * ldv<F32>(vol, cb + i01)
                   + wsw * ldv<F32>(vol, cb + i10) + wse * ldv<F32>(vol, cb + i11);
        }
    }
    #pragma unroll
    for (int c = 0; c < 32; c++) fx[c] *= (1.0f / 3.0f);

    const float* W1 = wsm;
    const float* B1 = wsm + 2048;
    const float* W2 = wsm + 2112;
    const float* B2 = wsm + 4224;

    float h[64];
    #pragma unroll
    for (int j = 0; j < 64; j++) h[j] = B1[j];
    #pragma unroll
    for (int c = 0; c < 32; c++) {
        const float f = fx[c];
        #pragma unroll
        for (int j = 0; j < 64; j++) h[j] = fmaf(f, W1[c * 64 + j], h[j]);
    }
    #pragma unroll
    for (int j = 0; j < 64; j++) h[j] = softplus_f(h[j]);

    #pragma unroll 1
    for (int k = 0; k < 33; k++) {
        float zz = B2[k];
        #pragma unroll
        for (int j = 0; j < 64; j++) zz = fmaf(h[j], W2[j * 33 + k], zz);
        if (k == 0) {
            sigL[rl][s] = zz;
        } else {
            const float sg = 1.0f / (1.0f + expf(-zz));
            rgbL[rl][s][k - 1] = fmaf(sg, 1.002f, -0.001f);
        }
    }
    __syncthreads();

    const int c = t & 31;
    const float delta = 1.05f / 32.0f;
    float T = 1.0f, acc = 0.0f;
    float sig_prev = sigL[rl][0];
    float rgb_prev = rgbL[rl][0][c];
    #pragma unroll 1
    for (int sm = 0; sm < 31; sm++) {
        const float sig_next = sigL[rl][sm + 1];
        const float rgb_next = rgbL[rl][sm + 1][c];
        const float dm = 0.5f * (sig_prev + sig_next) - 1.0f;
        const float dens = softplus_f(dm);
        const float alpha = 1.0f - expf(-delta * dens);
        const float w = alpha * T;
        T *= (1.0f - alpha + 1e-10f);
        acc += w * 0.5f * (rgb_prev + rgb_next);
        sig_prev = sig_next;
        rgb_prev = rgb_next;
    }
    const size_t oidx = (size_t)gray * 32 + c;
    if (F32) ((float*)outp)[oidx] = acc;
    else     ((unsigned short*)outp)[oidx] = f2bf(acc);
}

__global__ __launch_bounds__(256) void render_any(
    const void* __restrict__ vol, const void* __restrict__ rayo,
    const void* __restrict__ rayd, const void* __restrict__ w1b,
    const void* __restrict__ b1b, const void* __restrict__ w2b,
    const void* __restrict__ b2b, void* __restrict__ outp,
    const int* __restrict__ flag)
{
    __shared__ float wsm[NWTS];
    __shared__ float rgbL[RAYS_PER_BLOCK][SS][33];
    __shared__ float sigL[RAYS_PER_BLOCK][SS];
    if (*flag) render_body<true >(vol, rayo, rayd, w1b, b1b, w2b, b2b, outp, wsm, rgbL, sigL);
    else       render_body<false>(vol, rayo, rayd, w1b, b1b, w2b, b2b, outp, wsm, rgbL, sigL);
}

extern "C" void kernel_launch(void* const* d_in, const int* in_sizes, int n_in,
                              void* d_out, int out_size, void* d_ws, size_t ws_size,
                              hipStream_t stream) {
    const void* vol  = d_in[0];
    const void* rayo = d_in[1];
    const void* rayd = d_in[2];
    const void* w1   = d_in[3];
    const void* b1   = d_in[4];
    const void* w2   = d_in[5];
    const void* b2   = d_in[6];
    int* flag = (int*)d_ws;
    void* tex = (void*)((char*)d_ws + TEXOFF);

    const size_t need = TEXOFF + (size_t)6 * HH * WW * CC * 4;   // f32 worst case: 50.6 MB

    detect_dtype<<<dim3(1), dim3(64), 0, stream>>>(rayo, flag);
    if (ws_size >= need) {
        transpose_tex<<<dim3(WW / 32, HH, 6), dim3(32, 32), 0, stream>>>(vol, tex, flag);
        render_fast<<<dim3(NRAYS / RAYS_PER_BLOCK), dim3(256), 0, stream>>>(
            tex, rayo, rayd, w1, b1, w2, b2, d_out, flag);
    } else {
        render_any<<<dim3(NRAYS / RAYS_PER_BLOCK), dim3(256), 0, stream>>>(
            vol, rayo, rayd, w1, b1, w2, b2, d_out, flag);
    }
}